// Round 9
// baseline (2566.683 us; speedup 1.0000x reference)
//
#include <hip/hip_runtime.h>

typedef __attribute__((ext_vector_type(8))) short bfrag;   // 8 bf16 (4 VGPRs)
typedef __attribute__((ext_vector_type(4))) float f32x4;   // MFMA C/D
typedef __attribute__((ext_vector_type(4))) int i32x4;     // 16B moves

#define NT 512      // seq len
#define NB 64       // batch
#define KD 512      // D == H == 512
#define NG 2048     // 4*H gate rows
#define GB 4        // batch blocks (16 batch each)
#define GH 16       // h-slices (32 dims each)

#define YS_SZ (NT * NB * KD)          // 16777216
#define HT_OFF YS_SZ
#define CT_OFF (YS_SZ + NB * KD)

// mailbox: [2 parity][GB blocks][256 pairs][16 batch] of u64 {tag32 | bf16x2}
#define MB_BLK_WORDS 4096
#define MB_PAR_WORDS (GB * MB_BLK_WORDS)
#define MB_BYTES (2 * MB_PAR_WORDS * 8)   // 262144

__device__ __forceinline__ unsigned short f2bf(float f) {
  unsigned u = __float_as_uint(f);
  u += 0x7fffu + ((u >> 16) & 1u);
  return (unsigned short)(u >> 16);
}
__device__ __forceinline__ float bf2f(unsigned short h) {
  return __uint_as_float(((unsigned)h) << 16);
}
__device__ __forceinline__ float sigm(float v) { return 1.f / (1.f + __expf(-v)); }
__device__ __forceinline__ float tanh_f(float v) { return 1.f - 2.f / (__expf(2.f * v) + 1.f); }

// ---------------- fp32 -> bf16 convert (vectorized) ----------------
__global__ __launch_bounds__(256) void cvt_bf16(const float* __restrict__ src,
                                                unsigned short* __restrict__ dst, int n8) {
  int i = blockIdx.x * 256 + threadIdx.x;
  if (i >= n8) return;
  const float4 a = *(const float4*)(src + (size_t)i * 8);
  const float4 b = *(const float4*)(src + (size_t)i * 8 + 4);
  i32x4 v;
  v.x = (int)(f2bf(a.x) | ((unsigned)f2bf(a.y) << 16));
  v.y = (int)(f2bf(a.z) | ((unsigned)f2bf(a.w) << 16));
  v.z = (int)(f2bf(b.x) | ((unsigned)f2bf(b.y) << 16));
  v.w = (int)(f2bf(b.z) | ((unsigned)f2bf(b.w) << 16));
  *(i32x4*)(dst + (size_t)i * 8) = v;
}

// ---------------- Phase A: x_proj[t][n][b] = sum_k W_ih[n][k]*x[t][b][k] + b_ih[n] --------
template <int XP32>
__global__ __launch_bounds__(256) void xproj_gemm(const unsigned short* __restrict__ Wb,
                                                  const unsigned short* __restrict__ Xb,
                                                  const float* __restrict__ bias,
                                                  void* __restrict__ XPv) {
  __shared__ unsigned short Wt[64 * 40];
  __shared__ unsigned short Xt[64 * 40];
  const int tid = threadIdx.x;
  const int lane = tid & 63, wid = tid >> 6;
  const int g = lane >> 4, cc = lane & 15;
  const int n0 = blockIdx.x * 64;
  const int t = blockIdx.y;
  const size_t m0 = (size_t)t * 64;
  const int srow = tid >> 2, schunk = (tid & 3) * 8;

  f32x4 acc[4] = {};
  for (int kb = 0; kb < KD; kb += 32) {
    __syncthreads();
    *(i32x4*)&Wt[srow * 40 + schunk] = *(const i32x4*)(Wb + (size_t)(n0 + srow) * KD + kb + schunk);
    *(i32x4*)&Xt[srow * 40 + schunk] = *(const i32x4*)(Xb + (m0 + srow) * KD + kb + schunk);
    __syncthreads();
    bfrag af = *(const bfrag*)&Wt[(wid * 16 + cc) * 40 + g * 8];
#pragma unroll
    for (int mt = 0; mt < 4; ++mt) {
      bfrag bf = *(const bfrag*)&Xt[(mt * 16 + cc) * 40 + g * 8];
      acc[mt] = __builtin_amdgcn_mfma_f32_16x16x32_bf16(af, bf, acc[mt], 0, 0, 0);
    }
  }
  const int nl = wid * 16 + g * 4;
  float bi[4];
#pragma unroll
  for (int r = 0; r < 4; ++r) bi[r] = bias[n0 + nl + r];
#pragma unroll
  for (int mt = 0; mt < 4; ++mt) {
#pragma unroll
    for (int r = 0; r < 4; ++r) {
      float v = acc[mt][r] + bi[r];
      size_t idx = ((size_t)t * NG + n0 + nl + r) * 64 + mt * 16 + cc;
      if (XP32) ((float*)XPv)[idx] = v;
      else ((unsigned short*)XPv)[idx] = f2bf(v);
    }
  }
}

// ---------------- Phase B: persistent recurrence, 2-chain multiplex ----------------
// grid = 32: slice = bid&15 (32 dims), pair = bid>>4; WG serves batch-blocks
// {2*pair, 2*pair+1} — two INDEPENDENT recurrences time-multiplexed so each chain's
// mailbox round-trip hides behind the other chain's compute+publish. W_hh registers
// are shared across chains (same weights, different batches). Transport per chain =
// R6's tagged-data mailbox (single-hop u64 {tag|bf16x2}, exact-tag accept, parity-2,
// relaxed agent scope, no fences, full re-issue poll rounds).
template <int XP32>
__global__ __launch_bounds__(256, 1) void lstm_rec(const unsigned short* __restrict__ Whh,
                                                   const void* __restrict__ XPv,
                                                   const float* __restrict__ bhh,
                                                   const float* __restrict__ h0,
                                                   const float* __restrict__ c0,
                                                   unsigned long long* __restrict__ mbox,
                                                   float* __restrict__ out) {
  __shared__ unsigned short hl[2][16 * 512];  // per-chain h block, XOR-swizzled (2x16KB)

  const int tid = threadIdx.x;
  const int lane = tid & 63, wid = tid >> 6;
  const int g = lane >> 4, cc = lane & 15;
  const int slice = blockIdx.x & 15, pair = blockIdx.x >> 4;
  const int d0 = slice * 32;

  // ---- publish h0 slices (tag=1) for BOTH chains into parity-0 mailbox, ASAP
#pragma unroll
  for (int cix = 0; cix < 2; ++cix) {
    const int blk = pair * 2 + cix, b0 = blk * 16;
    const int lp = tid >> 4, b = tid & 15;  // local pair, batch row
    const int d = d0 + lp * 2;
    const float* hp = h0 + (size_t)(b0 + b) * KD + d;
    unsigned d32 = (unsigned)f2bf(hp[0]) | ((unsigned)f2bf(hp[1]) << 16);
    __hip_atomic_store(mbox + (size_t)blk * MB_BLK_WORDS + ((d0 >> 1) + lp) * 16 + b,
                       (1ull << 32) | (unsigned long long)d32, __ATOMIC_RELAXED,
                       __HIP_MEMORY_SCOPE_AGENT);
  }

  // ---- preload W_hh slice into registers: 2 tiles x 16 k-steps of bf16x8 (shared)
  bfrag w[2][16];
#pragma unroll
  for (int j = 0; j < 2; ++j) {
    const int tt = wid * 2 + j;
    const int r = tt * 16 + cc;  // A-operand row = lane&15
    const size_t n = (size_t)(r & 3) * KD + d0 + (r >> 2);
#pragma unroll
    for (int ks = 0; ks < 16; ++ks)
      w[j][ks] = *(const bfrag*)(Whh + n * KD + ks * 32 + g * 8);
  }
  float bh[2][4];
#pragma unroll
  for (int j = 0; j < 2; ++j) {
    const int d = d0 + (wid * 2 + j) * 4 + g;
#pragma unroll
    for (int r = 0; r < 4; ++r) bh[j][r] = bhh[r * KD + d];
  }
  float creg[2][2];
#pragma unroll
  for (int cix = 0; cix < 2; ++cix) {
    const int b0 = (pair * 2 + cix) * 16;
#pragma unroll
    for (int j = 0; j < 2; ++j)
      creg[cix][j] = c0[(size_t)(b0 + cc) * KD + d0 + (wid * 2 + j) * 4 + g];
  }

  unsigned long long q0, q1, q2, q3, q4, q5, q6, q7, q8, q9, q10, q11, q12, q13, q14, q15;

#define PISSUE(MB, r)                                                       \
  asm volatile("global_load_dwordx2 %0, %1, %2 sc1"                         \
               : "=v"(q##r)                                                 \
               : "v"((unsigned)(tid * 8 + (r) * 2048)), "s"(MB) : "memory")
#define PISSUE_ALL(MB)                                                      \
  do {                                                                      \
    PISSUE(MB, 0); PISSUE(MB, 1); PISSUE(MB, 2); PISSUE(MB, 3);             \
    PISSUE(MB, 4); PISSUE(MB, 5); PISSUE(MB, 6); PISSUE(MB, 7);             \
    PISSUE(MB, 8); PISSUE(MB, 9); PISSUE(MB, 10); PISSUE(MB, 11);           \
    PISSUE(MB, 12); PISSUE(MB, 13); PISSUE(MB, 14); PISSUE(MB, 15);         \
  } while (0)
#define PCHK_ALL(okv, tg)                                                   \
  do {                                                                      \
    okv = 1u;                                                               \
    okv &= ((unsigned)(q0 >> 32) == (tg)); okv &= ((unsigned)(q1 >> 32) == (tg));   \
    okv &= ((unsigned)(q2 >> 32) == (tg)); okv &= ((unsigned)(q3 >> 32) == (tg));   \
    okv &= ((unsigned)(q4 >> 32) == (tg)); okv &= ((unsigned)(q5 >> 32) == (tg));   \
    okv &= ((unsigned)(q6 >> 32) == (tg)); okv &= ((unsigned)(q7 >> 32) == (tg));   \
    okv &= ((unsigned)(q8 >> 32) == (tg)); okv &= ((unsigned)(q9 >> 32) == (tg));   \
    okv &= ((unsigned)(q10 >> 32) == (tg)); okv &= ((unsigned)(q11 >> 32) == (tg)); \
    okv &= ((unsigned)(q12 >> 32) == (tg)); okv &= ((unsigned)(q13 >> 32) == (tg)); \
    okv &= ((unsigned)(q14 >> 32) == (tg)); okv &= ((unsigned)(q15 >> 32) == (tg)); \
  } while (0)

  for (int t = 0; t < NT; ++t) {
    const int par = t & 1;
    const unsigned tg = (unsigned)(t + 1);
    const unsigned long long tagn = (unsigned long long)(unsigned)(t + 2) << 32;
#pragma unroll
    for (int cix = 0; cix < 2; ++cix) {
      const int blk = pair * 2 + cix, b0 = blk * 16;
      // ---- xp loads for this chain/step (drained by the poll's vmcnt(0))
      unsigned xpr[2][4];
#pragma unroll
      for (int j = 0; j < 2; ++j) {
        const int d = d0 + (wid * 2 + j) * 4 + g;
#pragma unroll
        for (int r = 0; r < 4; ++r) {
          const size_t idx = ((size_t)t * NG + r * KD + d) * 64 + b0 + cc;
          if constexpr (XP32) {
            const float* p = (const float*)XPv + idx;
            asm volatile("global_load_dword %0, %1, off" : "=v"(xpr[j][r]) : "v"(p) : "memory");
          } else {
            const unsigned short* p = (const unsigned short*)XPv + idx;
            asm volatile("global_load_ushort %0, %1, off" : "=v"(xpr[j][r]) : "v"(p) : "memory");
          }
        }
      }
      // ---- poll this chain's h_t (single-hop tagged data)
      const unsigned long long* mbr =
          mbox + (size_t)par * MB_PAR_WORDS + (size_t)blk * MB_BLK_WORDS;
      unsigned ok;
      for (;;) {
        PISSUE_ALL(mbr);
        asm volatile("s_waitcnt vmcnt(0)" ::: "memory");
        __builtin_amdgcn_sched_barrier(0);
        PCHK_ALL(ok, tg);
        if (__all(ok)) break;
      }
      // ---- unpack into this chain's swizzled LDS buffer
      {
        char* hlb = (char*)&hl[cix][0];
        const int b = tid & 15, pq = tid >> 4;
        const int bb = b * 1024, bx = (b & 7) << 4;
#define PUNP(r) *(unsigned*)(hlb + bb + ((((r)*16 + pq) * 4) ^ bx)) = (unsigned)q##r;
        PUNP(0) PUNP(1) PUNP(2) PUNP(3) PUNP(4) PUNP(5) PUNP(6) PUNP(7)
        PUNP(8) PUNP(9) PUNP(10) PUNP(11) PUNP(12) PUNP(13) PUNP(14) PUNP(15)
#undef PUNP
      }
      __syncthreads();
      // ---- gates = W_slice @ h^T (4 accumulators, chains of 8)
      const char* hrb = (const char*)&hl[cix][0] + cc * 1024;
      const int cx = (cc & 7) << 4;
      f32x4 p00 = {0.f, 0.f, 0.f, 0.f}, p01 = {0.f, 0.f, 0.f, 0.f};
      f32x4 p10 = {0.f, 0.f, 0.f, 0.f}, p11 = {0.f, 0.f, 0.f, 0.f};
#pragma unroll
      for (int ks = 0; ks < 8; ++ks) {
        const int off = ks * 64 + g * 16;
        bfrag hb = *(const bfrag*)(hrb + (off ^ cx));
        p00 = __builtin_amdgcn_mfma_f32_16x16x32_bf16(w[0][ks], hb, p00, 0, 0, 0);
        p10 = __builtin_amdgcn_mfma_f32_16x16x32_bf16(w[1][ks], hb, p10, 0, 0, 0);
      }
#pragma unroll
      for (int ks = 8; ks < 16; ++ks) {
        const int off = ks * 64 + g * 16;
        bfrag hb = *(const bfrag*)(hrb + (off ^ cx));
        p01 = __builtin_amdgcn_mfma_f32_16x16x32_bf16(w[0][ks], hb, p01, 0, 0, 0);
        p11 = __builtin_amdgcn_mfma_f32_16x16x32_bf16(w[1][ks], hb, p11, 0, 0, 0);
      }
      const f32x4 acc0 = p00 + p01, acc1 = p10 + p11;
      // ---- pointwise (xp drained by the poll's vmcnt(0))
      float hnv[2];
#pragma unroll
      for (int j = 0; j < 2; ++j) {
        const f32x4 a = j ? acc1 : acc0;
        float x0, x1, x2, x3;
        if constexpr (XP32) {
          x0 = __uint_as_float(xpr[j][0]); x1 = __uint_as_float(xpr[j][1]);
          x2 = __uint_as_float(xpr[j][2]); x3 = __uint_as_float(xpr[j][3]);
        } else {
          x0 = bf2f((unsigned short)xpr[j][0]); x1 = bf2f((unsigned short)xpr[j][1]);
          x2 = bf2f((unsigned short)xpr[j][2]); x3 = bf2f((unsigned short)xpr[j][3]);
        }
        float gi = a[0] + x0 + bh[j][0];
        float gf = a[1] + x1 + bh[j][1];
        float gg = a[2] + x2 + bh[j][2];
        float go = a[3] + x3 + bh[j][3];
        float cn = sigm(gf) * creg[cix][j] + sigm(gi) * tanh_f(gg);
        creg[cix][j] = cn;
        hnv[j] = sigm(go) * tanh_f(cn);
      }
      // ---- single-hop publish: pair dims via shfl, store (tag|bf16x2) words NOW; no drain
      {
        unsigned long long* mbw =
            mbox + (size_t)(par ^ 1) * MB_PAR_WORDS + (size_t)blk * MB_BLK_WORDS;
        const float o0 = __shfl_xor(hnv[0], 16);
        const float o1 = __shfl_xor(hnv[1], 16);
        if (!(g & 1)) {
          const unsigned w0 = (unsigned)f2bf(hnv[0]) | ((unsigned)f2bf(o0) << 16);
          const unsigned w1 = (unsigned)f2bf(hnv[1]) | ((unsigned)f2bf(o1) << 16);
          const int p0 = (d0 >> 1) + wid * 4 + (g >> 1);
          const int p1 = p0 + 2;
          __hip_atomic_store(mbw + p0 * 16 + cc, tagn | (unsigned long long)w0,
                             __ATOMIC_RELAXED, __HIP_MEMORY_SCOPE_AGENT);
          __hip_atomic_store(mbw + p1 * 16 + cc, tagn | (unsigned long long)w1,
                             __ATOMIC_RELAXED, __HIP_MEMORY_SCOPE_AGENT);
        }
      }
      // ---- direct output stores from registers (fire-and-forget)
      {
        float* yb = out + (size_t)t * NB * KD + (size_t)(b0 + cc) * KD + d0 + wid * 8 + g;
        yb[0] = hnv[0];
        yb[4] = hnv[1];
        if (t == NT - 1) {
          float* hb = out + HT_OFF + (size_t)(b0 + cc) * KD + d0 + wid * 8 + g;
          hb[0] = hnv[0];
          hb[4] = hnv[1];
          float* cb = out + CT_OFF + (size_t)(b0 + cc) * KD + d0 + wid * 8 + g;
          cb[0] = creg[cix][0];
          cb[4] = creg[cix][1];
        }
      }
    }
  }
#undef PISSUE
#undef PISSUE_ALL
#undef PCHK_ALL
}

extern "C" void kernel_launch(void* const* d_in, const int* in_sizes, int n_in,
                              void* d_out, int out_size, void* d_ws, size_t ws_size,
                              hipStream_t stream) {
  const float* x = (const float*)d_in[0];
  const float* h0 = (const float*)d_in[1];
  const float* c0 = (const float*)d_in[2];
  const float* Wih = (const float*)d_in[3];
  const float* Whh = (const float*)d_in[4];
  const float* bih = (const float*)d_in[5];
  const float* bhh = (const float*)d_in[6];
  float* out = (float*)d_out;
  char* ws = (char*)d_ws;

  unsigned long long* mbox = (unsigned long long*)ws;                      // 256KB
  unsigned short* WhhB = (unsigned short*)(ws + MB_BYTES);                 // 2MB
  unsigned short* WihB = (unsigned short*)(ws + MB_BYTES + 2097152);       // 2MB
  unsigned short* XB = (unsigned short*)(ws + MB_BYTES + 2 * 2097152);     // 32MB
  const size_t xp_off = MB_BYTES + 2ull * 2097152 + 33554432;
  void* XP = (void*)(ws + xp_off);
  const bool xp32 = ws_size >= xp_off + (size_t)NT * NG * 64 * 4;

  hipMemsetAsync(ws, 0, MB_BYTES, stream);  // reset mailbox tags (poison/replay safe)

  const int nx8 = NT * NB * KD / 8;
  const int nw8 = NG * KD / 8;
  cvt_bf16<<<dim3(nx8 / 256), 256, 0, stream>>>(x, XB, nx8);
  cvt_bf16<<<dim3(nw8 / 256), 256, 0, stream>>>(Wih, WihB, nw8);
  cvt_bf16<<<dim3(nw8 / 256), 256, 0, stream>>>(Whh, WhhB, nw8);

  if (xp32) {
    xproj_gemm<1><<<dim3(NG / 64, NT), 256, 0, stream>>>(WihB, XB, bih, XP);
    lstm_rec<1><<<dim3(GB * GH / 2), 256, 0, stream>>>(WhhB, XP, bhh, h0, c0, mbox, out);
  } else {
    xproj_gemm<0><<<dim3(NG / 64, NT), 256, 0, stream>>>(WihB, XB, bih, XP);
    lstm_rec<0><<<dim3(GB * GH / 2), 256, 0, stream>>>(WhhB, XP, bhh, h0, c0, mbox, out);
  }
}

// Round 10
// 2367.325 us; speedup vs baseline: 1.0842x; 1.0842x over previous
//
#include <hip/hip_runtime.h>

typedef __attribute__((ext_vector_type(8))) short bfrag;   // 8 bf16 (4 VGPRs)
typedef __attribute__((ext_vector_type(4))) float f32x4;   // MFMA C/D
typedef __attribute__((ext_vector_type(4))) int i32x4;     // 16B moves

#define NT 512      // seq len
#define NB 64       // batch
#define KD 512      // D == H == 512
#define NG 2048     // 4*H gate rows
#define GB 4        // batch blocks (16 batch each)

#define YS_SZ (NT * NB * KD)
#define HT_OFF YS_SZ
#define CT_OFF (YS_SZ + NB * KD)

// mailbox: [2 parity][GB blocks][256 pairs][16 batch] of u64 {tag32 | bf16x2}
#define MB_BLK_WORDS 4096
#define MB_PAR_WORDS (GB * MB_BLK_WORDS)
#define MB_BYTES (2 * MB_PAR_WORDS * 8)   // 262144

__device__ __forceinline__ unsigned short f2bf(float f) {
  unsigned u = __float_as_uint(f);
  u += 0x7fffu + ((u >> 16) & 1u);
  return (unsigned short)(u >> 16);
}
__device__ __forceinline__ float bf2f(unsigned short h) {
  return __uint_as_float(((unsigned)h) << 16);
}
__device__ __forceinline__ float sigm(float v) { return 1.f / (1.f + __expf(-v)); }
__device__ __forceinline__ float tanh_f(float v) { return 1.f - 2.f / (__expf(2.f * v) + 1.f); }

// ---------------- fp32 -> bf16 convert (vectorized) ----------------
__global__ __launch_bounds__(256) void cvt_bf16(const float* __restrict__ src,
                                                unsigned short* __restrict__ dst, int n8) {
  int i = blockIdx.x * 256 + threadIdx.x;
  if (i >= n8) return;
  const float4 a = *(const float4*)(src + (size_t)i * 8);
  const float4 b = *(const float4*)(src + (size_t)i * 8 + 4);
  i32x4 v;
  v.x = (int)(f2bf(a.x) | ((unsigned)f2bf(a.y) << 16));
  v.y = (int)(f2bf(a.z) | ((unsigned)f2bf(a.w) << 16));
  v.z = (int)(f2bf(b.x) | ((unsigned)f2bf(b.y) << 16));
  v.w = (int)(f2bf(b.z) | ((unsigned)f2bf(b.w) << 16));
  *(i32x4*)(dst + (size_t)i * 8) = v;
}

// ---------------- Phase A: x_proj ----------------
template <int XP32>
__global__ __launch_bounds__(256) void xproj_gemm(const unsigned short* __restrict__ Wb,
                                                  const unsigned short* __restrict__ Xb,
                                                  const float* __restrict__ bias,
                                                  void* __restrict__ XPv) {
  __shared__ unsigned short Wt[64 * 40];
  __shared__ unsigned short Xt[64 * 40];
  const int tid = threadIdx.x;
  const int lane = tid & 63, wid = tid >> 6;
  const int g = lane >> 4, cc = lane & 15;
  const int n0 = blockIdx.x * 64;
  const int t = blockIdx.y;
  const size_t m0 = (size_t)t * 64;
  const int srow = tid >> 2, schunk = (tid & 3) * 8;

  f32x4 acc[4] = {};
  for (int kb = 0; kb < KD; kb += 32) {
    __syncthreads();
    *(i32x4*)&Wt[srow * 40 + schunk] = *(const i32x4*)(Wb + (size_t)(n0 + srow) * KD + kb + schunk);
    *(i32x4*)&Xt[srow * 40 + schunk] = *(const i32x4*)(Xb + (m0 + srow) * KD + kb + schunk);
    __syncthreads();
    bfrag af = *(const bfrag*)&Wt[(wid * 16 + cc) * 40 + g * 8];
#pragma unroll
    for (int mt = 0; mt < 4; ++mt) {
      bfrag bf = *(const bfrag*)&Xt[(mt * 16 + cc) * 40 + g * 8];
      acc[mt] = __builtin_amdgcn_mfma_f32_16x16x32_bf16(af, bf, acc[mt], 0, 0, 0);
    }
  }
  const int nl = wid * 16 + g * 4;
  float bi[4];
#pragma unroll
  for (int r = 0; r < 4; ++r) bi[r] = bias[n0 + nl + r];
#pragma unroll
  for (int mt = 0; mt < 4; ++mt) {
#pragma unroll
    for (int r = 0; r < 4; ++r) {
      float v = acc[mt][r] + bi[r];
      size_t idx = ((size_t)t * NG + n0 + nl + r) * 64 + mt * 16 + cc;
      if (XP32) ((float*)XPv)[idx] = v;
      else ((unsigned short*)XPv)[idx] = f2bf(v);
    }
  }
}

// ---------------- Phase B: persistent recurrence, 2-chain SPLIT-WAIT pipeline ----------
// grid = 32: slice = bid&15 (32 dims), pair = bid>>4; WG serves batch-blocks
// {2*pair, 2*pair+1}. Each chain's poll RT hides under the OTHER chain's
// MFMA+PW via counted suffix-waits (vmcnt(N), N = my asm ops issued after the
// group; in-order completion makes compiler extras safe — they only strengthen
// the wait). Transport per chain = R6's tagged-data mailbox.
template <int XP32>
__global__ __launch_bounds__(256, 1) void lstm_rec(const unsigned short* __restrict__ Whh,
                                                   const void* __restrict__ XPv,
                                                   const float* __restrict__ bhh,
                                                   const float* __restrict__ h0,
                                                   const float* __restrict__ c0,
                                                   unsigned long long* __restrict__ mbox,
                                                   float* __restrict__ out) {
  __shared__ unsigned short hl0[16 * 512];  // chain A h block, XOR-swizzled (16KB)
  __shared__ unsigned short hl1[16 * 512];  // chain B h block (16KB)

  const int tid = threadIdx.x;
  const int lane = tid & 63, wid = tid >> 6;
  const int g = lane >> 4, cc = lane & 15;
  const int slice = blockIdx.x & 15, pair = blockIdx.x >> 4;
  const int d0 = slice * 32;
  const int blkA = pair * 2, blkB = pair * 2 + 1;
  const int b0A = blkA * 16, b0B = blkB * 16;

  // ---- publish h0 slices (tag=1) for BOTH chains into parity-0 mailbox, ASAP
#pragma unroll
  for (int cix = 0; cix < 2; ++cix) {
    const int blk = cix ? blkB : blkA, b0 = blk * 16;
    const int lp = tid >> 4, b = tid & 15;
    const int d = d0 + lp * 2;
    const float* hp = h0 + (size_t)(b0 + b) * KD + d;
    unsigned d32 = (unsigned)f2bf(hp[0]) | ((unsigned)f2bf(hp[1]) << 16);
    __hip_atomic_store(mbox + (size_t)blk * MB_BLK_WORDS + ((d0 >> 1) + lp) * 16 + b,
                       (1ull << 32) | (unsigned long long)d32, __ATOMIC_RELAXED,
                       __HIP_MEMORY_SCOPE_AGENT);
  }

  // ---- preload W_hh slice (shared across chains): 2 tiles x 16 k-steps
  bfrag w[2][16];
#pragma unroll
  for (int j = 0; j < 2; ++j) {
    const int tt = wid * 2 + j;
    const int r = tt * 16 + cc;
    const size_t n = (size_t)(r & 3) * KD + d0 + (r >> 2);
#pragma unroll
    for (int ks = 0; ks < 16; ++ks)
      w[j][ks] = *(const bfrag*)(Whh + n * KD + ks * 32 + g * 8);
  }
  float bh[2][4];
#pragma unroll
  for (int j = 0; j < 2; ++j) {
    const int d = d0 + (wid * 2 + j) * 4 + g;
#pragma unroll
    for (int r = 0; r < 4; ++r) bh[j][r] = bhh[r * KD + d];
  }
  float cregA0 = c0[(size_t)(b0A + cc) * KD + d0 + wid * 8 + g];
  float cregA1 = c0[(size_t)(b0A + cc) * KD + d0 + wid * 8 + 4 + g];
  float cregB0 = c0[(size_t)(b0B + cc) * KD + d0 + wid * 8 + g];
  float cregB1 = c0[(size_t)(b0B + cc) * KD + d0 + wid * 8 + 4 + g];

  unsigned long long q0, q1, q2, q3, q4, q5, q6, q7, q8, q9, q10, q11, q12, q13, q14, q15;

#define PISSUE(MB, r)                                                       \
  asm volatile("global_load_dwordx2 %0, %1, %2 sc1"                         \
               : "=v"(q##r)                                                 \
               : "v"((unsigned)(tid * 8 + (r) * 2048)), "s"(MB) : "memory")
#define PISSUE_ALL(MB)                                                      \
  do {                                                                      \
    PISSUE(MB, 0); PISSUE(MB, 1); PISSUE(MB, 2); PISSUE(MB, 3);             \
    PISSUE(MB, 4); PISSUE(MB, 5); PISSUE(MB, 6); PISSUE(MB, 7);             \
    PISSUE(MB, 8); PISSUE(MB, 9); PISSUE(MB, 10); PISSUE(MB, 11);           \
    PISSUE(MB, 12); PISSUE(MB, 13); PISSUE(MB, 14); PISSUE(MB, 15);         \
  } while (0)
#define PCHK_ALL(okv, tg)                                                   \
  do {                                                                      \
    okv = 1u;                                                               \
    okv &= ((unsigned)(q0 >> 32) == (tg)); okv &= ((unsigned)(q1 >> 32) == (tg));   \
    okv &= ((unsigned)(q2 >> 32) == (tg)); okv &= ((unsigned)(q3 >> 32) == (tg));   \
    okv &= ((unsigned)(q4 >> 32) == (tg)); okv &= ((unsigned)(q5 >> 32) == (tg));   \
    okv &= ((unsigned)(q6 >> 32) == (tg)); okv &= ((unsigned)(q7 >> 32) == (tg));   \
    okv &= ((unsigned)(q8 >> 32) == (tg)); okv &= ((unsigned)(q9 >> 32) == (tg));   \
    okv &= ((unsigned)(q10 >> 32) == (tg)); okv &= ((unsigned)(q11 >> 32) == (tg)); \
    okv &= ((unsigned)(q12 >> 32) == (tg)); okv &= ((unsigned)(q13 >> 32) == (tg)); \
    okv &= ((unsigned)(q14 >> 32) == (tg)); okv &= ((unsigned)(q15 >> 32) == (tg)); \
  } while (0)
#define PUNPACK(HLB)                                                        \
  do {                                                                      \
    char* hlb_ = (char*)(HLB);                                              \
    const int b_ = tid & 15, pq_ = tid >> 4;                                \
    const int bb_ = b_ * 1024, bx_ = (b_ & 7) << 4;                         \
    *(unsigned*)(hlb_ + bb_ + (((0 * 16 + pq_) * 4) ^ bx_)) = (unsigned)q0;   \
    *(unsigned*)(hlb_ + bb_ + (((1 * 16 + pq_) * 4) ^ bx_)) = (unsigned)q1;   \
    *(unsigned*)(hlb_ + bb_ + (((2 * 16 + pq_) * 4) ^ bx_)) = (unsigned)q2;   \
    *(unsigned*)(hlb_ + bb_ + (((3 * 16 + pq_) * 4) ^ bx_)) = (unsigned)q3;   \
    *(unsigned*)(hlb_ + bb_ + (((4 * 16 + pq_) * 4) ^ bx_)) = (unsigned)q4;   \
    *(unsigned*)(hlb_ + bb_ + (((5 * 16 + pq_) * 4) ^ bx_)) = (unsigned)q5;   \
    *(unsigned*)(hlb_ + bb_ + (((6 * 16 + pq_) * 4) ^ bx_)) = (unsigned)q6;   \
    *(unsigned*)(hlb_ + bb_ + (((7 * 16 + pq_) * 4) ^ bx_)) = (unsigned)q7;   \
    *(unsigned*)(hlb_ + bb_ + (((8 * 16 + pq_) * 4) ^ bx_)) = (unsigned)q8;   \
    *(unsigned*)(hlb_ + bb_ + (((9 * 16 + pq_) * 4) ^ bx_)) = (unsigned)q9;   \
    *(unsigned*)(hlb_ + bb_ + (((10 * 16 + pq_) * 4) ^ bx_)) = (unsigned)q10; \
    *(unsigned*)(hlb_ + bb_ + (((11 * 16 + pq_) * 4) ^ bx_)) = (unsigned)q11; \
    *(unsigned*)(hlb_ + bb_ + (((12 * 16 + pq_) * 4) ^ bx_)) = (unsigned)q12; \
    *(unsigned*)(hlb_ + bb_ + (((13 * 16 + pq_) * 4) ^ bx_)) = (unsigned)q13; \
    *(unsigned*)(hlb_ + bb_ + (((14 * 16 + pq_) * 4) ^ bx_)) = (unsigned)q14; \
    *(unsigned*)(hlb_ + bb_ + (((15 * 16 + pq_) * 4) ^ bx_)) = (unsigned)q15; \
  } while (0)
#define XP_ISSUE(DST, T, B0)                                                \
  do {                                                                      \
    _Pragma("unroll") for (int j_ = 0; j_ < 2; ++j_) {                      \
      const int d_ = d0 + (wid * 2 + j_) * 4 + g;                           \
      _Pragma("unroll") for (int r_ = 0; r_ < 4; ++r_) {                    \
        const size_t idx_ = ((size_t)(T) * NG + r_ * KD + d_) * 64 + (B0) + cc; \
        if constexpr (XP32) {                                               \
          const float* p_ = (const float*)XPv + idx_;                       \
          asm volatile("global_load_dword %0, %1, off"                      \
                       : "=v"(DST[j_][r_]) : "v"(p_) : "memory");           \
        } else {                                                            \
          const unsigned short* p_ = (const unsigned short*)XPv + idx_;     \
          asm volatile("global_load_ushort %0, %1, off"                     \
                       : "=v"(DST[j_][r_]) : "v"(p_) : "memory");           \
        }                                                                   \
      }                                                                     \
    }                                                                       \
  } while (0)
#define VMCNT(N) do { asm volatile("s_waitcnt vmcnt(" #N ")" ::: "memory"); \
                      __builtin_amdgcn_sched_barrier(0); } while (0)
#define MFMA_BLOCK(HLB, ACC0, ACC1)                                         \
  do {                                                                      \
    const char* hrb_ = (const char*)(HLB) + cc * 1024;                      \
    const int cx_ = (cc & 7) << 4;                                          \
    f32x4 s00 = {0.f, 0.f, 0.f, 0.f}, s01 = {0.f, 0.f, 0.f, 0.f};           \
    f32x4 s10 = {0.f, 0.f, 0.f, 0.f}, s11 = {0.f, 0.f, 0.f, 0.f};           \
    _Pragma("unroll") for (int ks_ = 0; ks_ < 8; ++ks_) {                   \
      bfrag hb_ = *(const bfrag*)(hrb_ + ((ks_ * 64 + g * 16) ^ cx_));      \
      s00 = __builtin_amdgcn_mfma_f32_16x16x32_bf16(w[0][ks_], hb_, s00, 0, 0, 0); \
      s10 = __builtin_amdgcn_mfma_f32_16x16x32_bf16(w[1][ks_], hb_, s10, 0, 0, 0); \
    }                                                                       \
    _Pragma("unroll") for (int ks_ = 8; ks_ < 16; ++ks_) {                  \
      bfrag hb_ = *(const bfrag*)(hrb_ + ((ks_ * 64 + g * 16) ^ cx_));      \
      s01 = __builtin_amdgcn_mfma_f32_16x16x32_bf16(w[0][ks_], hb_, s01, 0, 0, 0); \
      s11 = __builtin_amdgcn_mfma_f32_16x16x32_bf16(w[1][ks_], hb_, s11, 0, 0, 0); \
    }                                                                       \
    ACC0 = s00 + s01; ACC1 = s10 + s11;                                     \
  } while (0)

  // prologue: pre-issue chain-A polls for t=0 (parity 0)
  {
    const unsigned long long* mbA0 = mbox + (size_t)blkA * MB_BLK_WORDS;
    PISSUE_ALL(mbA0);
  }

  unsigned xpA[2][4], xpB[2][4];

  for (int t = 0; t < NT; ++t) {
    const int par = t & 1;
    const unsigned tg = (unsigned)(t + 1);
    const unsigned long long tagn = (unsigned long long)(unsigned)(t + 2) << 32;
    const unsigned long long* mbrA = mbox + (size_t)par * MB_PAR_WORDS + (size_t)blkA * MB_BLK_WORDS;
    const unsigned long long* mbrB = mbox + (size_t)par * MB_PAR_WORDS + (size_t)blkB * MB_BLK_WORDS;
    unsigned long long* mbwA = mbox + (size_t)(par ^ 1) * MB_PAR_WORDS + (size_t)blkA * MB_BLK_WORDS;
    unsigned long long* mbwB = mbox + (size_t)(par ^ 1) * MB_PAR_WORDS + (size_t)blkB * MB_BLK_WORDS;

    // ================= chain A =================
    XP_ISSUE(xpA, t, b0A);      // 8 asm loads (newest)
    VMCNT(8);                   // suffix(8)=xpA  => pollA (pre-issued) complete
    unsigned ok;
    PCHK_ALL(ok, tg);
    while (!__all(ok)) {
      PISSUE_ALL(mbrA);
      VMCNT(0);
      PCHK_ALL(ok, tg);
    }
    PUNPACK(hl0);
    __syncthreads();
    PISSUE_ALL(mbrB);           // chain-B polls fly under MFMA A
    f32x4 accA0, accA1;
    MFMA_BLOCK(hl0, accA0, accA1);
    VMCNT(16);                  // suffix(16)=pollB => xpA complete
    float hnA0, hnA1;
    {
      float x00, x01, x02, x03, x10, x11, x12, x13;
      if constexpr (XP32) {
        x00 = __uint_as_float(xpA[0][0]); x01 = __uint_as_float(xpA[0][1]);
        x02 = __uint_as_float(xpA[0][2]); x03 = __uint_as_float(xpA[0][3]);
        x10 = __uint_as_float(xpA[1][0]); x11 = __uint_as_float(xpA[1][1]);
        x12 = __uint_as_float(xpA[1][2]); x13 = __uint_as_float(xpA[1][3]);
      } else {
        x00 = bf2f((unsigned short)xpA[0][0]); x01 = bf2f((unsigned short)xpA[0][1]);
        x02 = bf2f((unsigned short)xpA[0][2]); x03 = bf2f((unsigned short)xpA[0][3]);
        x10 = bf2f((unsigned short)xpA[1][0]); x11 = bf2f((unsigned short)xpA[1][1]);
        x12 = bf2f((unsigned short)xpA[1][2]); x13 = bf2f((unsigned short)xpA[1][3]);
      }
      float gi = accA0[0] + x00 + bh[0][0], gf = accA0[1] + x01 + bh[0][1];
      float gg = accA0[2] + x02 + bh[0][2], go = accA0[3] + x03 + bh[0][3];
      float cn = sigm(gf) * cregA0 + sigm(gi) * tanh_f(gg);
      cregA0 = cn; hnA0 = sigm(go) * tanh_f(cn);
      gi = accA1[0] + x10 + bh[1][0]; gf = accA1[1] + x11 + bh[1][1];
      gg = accA1[2] + x12 + bh[1][2]; go = accA1[3] + x13 + bh[1][3];
      cn = sigm(gf) * cregA1 + sigm(gi) * tanh_f(gg);
      cregA1 = cn; hnA1 = sigm(go) * tanh_f(cn);
    }
    {
      const float o0 = __shfl_xor(hnA0, 16);
      const float o1 = __shfl_xor(hnA1, 16);
      if (!(g & 1)) {
        const unsigned w0 = (unsigned)f2bf(hnA0) | ((unsigned)f2bf(o0) << 16);
        const unsigned w1 = (unsigned)f2bf(hnA1) | ((unsigned)f2bf(o1) << 16);
        const int p0 = (d0 >> 1) + wid * 4 + (g >> 1);
        __hip_atomic_store(mbwA + p0 * 16 + cc, tagn | (unsigned long long)w0,
                           __ATOMIC_RELAXED, __HIP_MEMORY_SCOPE_AGENT);
        __hip_atomic_store(mbwA + (p0 + 2) * 16 + cc, tagn | (unsigned long long)w1,
                           __ATOMIC_RELAXED, __HIP_MEMORY_SCOPE_AGENT);
      }
      float* yb = out + (size_t)t * NB * KD + (size_t)(b0A + cc) * KD + d0 + wid * 8 + g;
      yb[0] = hnA0;
      yb[4] = hnA1;
      if (t == NT - 1) {
        float* hb = out + HT_OFF + (size_t)(b0A + cc) * KD + d0 + wid * 8 + g;
        hb[0] = hnA0; hb[4] = hnA1;
        float* cb = out + CT_OFF + (size_t)(b0A + cc) * KD + d0 + wid * 8 + g;
        cb[0] = cregA0; cb[4] = cregA1;
      }
    }
    // ================= chain B =================
    XP_ISSUE(xpB, t, b0B);      // 8 asm loads (newest)
    VMCNT(8);                   // suffix(8)=xpB => pollB complete
    PCHK_ALL(ok, tg);
    while (!__all(ok)) {
      PISSUE_ALL(mbrB);
      VMCNT(0);
      PCHK_ALL(ok, tg);
    }
    PUNPACK(hl1);
    __syncthreads();
    {
      // pre-issue chain-A polls for t+1 (parity par^1); fly under MFMA B
      const unsigned long long* mbrA1 =
          mbox + (size_t)(par ^ 1) * MB_PAR_WORDS + (size_t)blkA * MB_BLK_WORDS;
      PISSUE_ALL(mbrA1);
    }
    f32x4 accB0, accB1;
    MFMA_BLOCK(hl1, accB0, accB1);
    VMCNT(16);                  // suffix(16)=pollA' => xpB complete
    float hnB0, hnB1;
    {
      float x00, x01, x02, x03, x10, x11, x12, x13;
      if constexpr (XP32) {
        x00 = __uint_as_float(xpB[0][0]); x01 = __uint_as_float(xpB[0][1]);
        x02 = __uint_as_float(xpB[0][2]); x03 = __uint_as_float(xpB[0][3]);
        x10 = __uint_as_float(xpB[1][0]); x11 = __uint_as_float(xpB[1][1]);
        x12 = __uint_as_float(xpB[1][2]); x13 = __uint_as_float(xpB[1][3]);
      } else {
        x00 = bf2f((unsigned short)xpB[0][0]); x01 = bf2f((unsigned short)xpB[0][1]);
        x02 = bf2f((unsigned short)xpB[0][2]); x03 = bf2f((unsigned short)xpB[0][3]);
        x10 = bf2f((unsigned short)xpB[1][0]); x11 = bf2f((unsigned short)xpB[1][1]);
        x12 = bf2f((unsigned short)xpB[1][2]); x13 = bf2f((unsigned short)xpB[1][3]);
      }
      float gi = accB0[0] + x00 + bh[0][0], gf = accB0[1] + x01 + bh[0][1];
      float gg = accB0[2] + x02 + bh[0][2], go = accB0[3] + x03 + bh[0][3];
      float cn = sigm(gf) * cregB0 + sigm(gi) * tanh_f(gg);
      cregB0 = cn; hnB0 = sigm(go) * tanh_f(cn);
      gi = accB1[0] + x10 + bh[1][0]; gf = accB1[1] + x11 + bh[1][1];
      gg = accB1[2] + x12 + bh[1][2]; go = accB1[3] + x13 + bh[1][3];
      cn = sigm(gf) * cregB1 + sigm(gi) * tanh_f(gg);
      cregB1 = cn; hnB1 = sigm(go) * tanh_f(cn);
    }
    {
      const float o0 = __shfl_xor(hnB0, 16);
      const float o1 = __shfl_xor(hnB1, 16);
      if (!(g & 1)) {
        const unsigned w0 = (unsigned)f2bf(hnB0) | ((unsigned)f2bf(o0) << 16);
        const unsigned w1 = (unsigned)f2bf(hnB1) | ((unsigned)f2bf(o1) << 16);
        const int p0 = (d0 >> 1) + wid * 4 + (g >> 1);
        __hip_atomic_store(mbwB + p0 * 16 + cc, tagn | (unsigned long long)w0,
                           __ATOMIC_RELAXED, __HIP_MEMORY_SCOPE_AGENT);
        __hip_atomic_store(mbwB + (p0 + 2) * 16 + cc, tagn | (unsigned long long)w1,
                           __ATOMIC_RELAXED, __HIP_MEMORY_SCOPE_AGENT);
      }
      float* yb = out + (size_t)t * NB * KD + (size_t)(b0B + cc) * KD + d0 + wid * 8 + g;
      yb[0] = hnB0;
      yb[4] = hnB1;
      if (t == NT - 1) {
        float* hb = out + HT_OFF + (size_t)(b0B + cc) * KD + d0 + wid * 8 + g;
        hb[0] = hnB0; hb[4] = hnB1;
        float* cb = out + CT_OFF + (size_t)(b0B + cc) * KD + d0 + wid * 8 + g;
        cb[0] = cregB0; cb[4] = cregB1;
      }
    }
  }
#undef PISSUE
#undef PISSUE_ALL
#undef PCHK_ALL
#undef PUNPACK
#undef XP_ISSUE
#undef VMCNT
#undef MFMA_BLOCK
}

extern "C" void kernel_launch(void* const* d_in, const int* in_sizes, int n_in,
                              void* d_out, int out_size, void* d_ws, size_t ws_size,
                              hipStream_t stream) {
  const float* x = (const float*)d_in[0];
  const float* h0 = (const float*)d_in[1];
  const float* c0 = (const float*)d_in[2];
  const float* Wih = (const float*)d_in[3];
  const float* Whh = (const float*)d_in[4];
  const float* bih = (const float*)d_in[5];
  const float* bhh = (const float*)d_in[6];
  float* out = (float*)d_out;
  char* ws = (char*)d_ws;

  unsigned long long* mbox = (unsigned long long*)ws;                      // 256KB
  unsigned short* WhhB = (unsigned short*)(ws + MB_BYTES);                 // 2MB
  unsigned short* WihB = (unsigned short*)(ws + MB_BYTES + 2097152);       // 2MB
  unsigned short* XB = (unsigned short*)(ws + MB_BYTES + 2 * 2097152);     // 32MB
  const size_t xp_off = MB_BYTES + 2ull * 2097152 + 33554432;
  void* XP = (void*)(ws + xp_off);
  const bool xp32 = ws_size >= xp_off + (size_t)NT * NG * 64 * 4;

  hipMemsetAsync(ws, 0, MB_BYTES, stream);  // reset mailbox tags (poison/replay safe)

  const int nx8 = NT * NB * KD / 8;
  const int nw8 = NG * KD / 8;
  cvt_bf16<<<dim3(nx8 / 256), 256, 0, stream>>>(x, XB, nx8);
  cvt_bf16<<<dim3(nw8 / 256), 256, 0, stream>>>(Wih, WihB, nw8);
  cvt_bf16<<<dim3(nw8 / 256), 256, 0, stream>>>(Whh, WhhB, nw8);

  if (xp32) {
    xproj_gemm<1><<<dim3(NG / 64, NT), 256, 0, stream>>>(WihB, XB, bih, XP);
    lstm_rec<1><<<dim3(GB * 16 / 2), 256, 0, stream>>>(WhhB, XP, bhh, h0, c0, mbox, out);
  } else {
    xproj_gemm<0><<<dim3(NG / 64, NT), 256, 0, stream>>>(WihB, XB, bih, XP);
    lstm_rec<0><<<dim3(GB * 16 / 2), 256, 0, stream>>>(WhhB, XP, bhh, h0, c0, mbox, out);
  }
}

// Round 11
// 1416.008 us; speedup vs baseline: 1.8126x; 1.6718x over previous
//
#include <hip/hip_runtime.h>

typedef __attribute__((ext_vector_type(8))) short bfrag;   // 8 bf16 (4 VGPRs)
typedef __attribute__((ext_vector_type(4))) float f32x4;   // MFMA C/D
typedef __attribute__((ext_vector_type(4))) int i32x4;     // 16B moves

#define NT 512      // seq len
#define NB 64       // batch
#define KD 512      // D == H == 512
#define NG 2048     // 4*H gate rows
#define GB 4        // batch blocks (16 batch each)
#define GH 16       // h-slices (32 dims each)

#define YS_SZ (NT * NB * KD)          // 16777216
#define HT_OFF YS_SZ
#define CT_OFF (YS_SZ + NB * KD)

// mailbox: [2 parity][GB blocks][256 pairs][16 batch] of u64 {tag32 | bf16x2}
#define MB_BLK_WORDS 4096
#define MB_PAR_WORDS (GB * MB_BLK_WORDS)
#define MB_BYTES (2 * MB_PAR_WORDS * 8)   // 262144

__device__ __forceinline__ unsigned short f2bf(float f) {
  unsigned u = __float_as_uint(f);
  u += 0x7fffu + ((u >> 16) & 1u);
  return (unsigned short)(u >> 16);
}
__device__ __forceinline__ float bf2f(unsigned short h) {
  return __uint_as_float(((unsigned)h) << 16);
}
__device__ __forceinline__ float sigm(float v) { return 1.f / (1.f + __expf(-v)); }
__device__ __forceinline__ float tanh_f(float v) { return 1.f - 2.f / (__expf(2.f * v) + 1.f); }

// ---------------- fp32 -> bf16 convert (vectorized) ----------------
__global__ __launch_bounds__(256) void cvt_bf16(const float* __restrict__ src,
                                                unsigned short* __restrict__ dst, int n8) {
  int i = blockIdx.x * 256 + threadIdx.x;
  if (i >= n8) return;
  const float4 a = *(const float4*)(src + (size_t)i * 8);
  const float4 b = *(const float4*)(src + (size_t)i * 8 + 4);
  i32x4 v;
  v.x = (int)(f2bf(a.x) | ((unsigned)f2bf(a.y) << 16));
  v.y = (int)(f2bf(a.z) | ((unsigned)f2bf(a.w) << 16));
  v.z = (int)(f2bf(b.x) | ((unsigned)f2bf(b.y) << 16));
  v.w = (int)(f2bf(b.z) | ((unsigned)f2bf(b.w) << 16));
  *(i32x4*)(dst + (size_t)i * 8) = v;
}

// ---------------- Phase A: x_proj[t][n][b] = sum_k W_ih[n][k]*x[t][b][k] + b_ih[n] --------
template <int XP32>
__global__ __launch_bounds__(256) void xproj_gemm(const unsigned short* __restrict__ Wb,
                                                  const unsigned short* __restrict__ Xb,
                                                  const float* __restrict__ bias,
                                                  void* __restrict__ XPv) {
  __shared__ unsigned short Wt[64 * 40];
  __shared__ unsigned short Xt[64 * 40];
  const int tid = threadIdx.x;
  const int lane = tid & 63, wid = tid >> 6;
  const int g = lane >> 4, cc = lane & 15;
  const int n0 = blockIdx.x * 64;
  const int t = blockIdx.y;
  const size_t m0 = (size_t)t * 64;
  const int srow = tid >> 2, schunk = (tid & 3) * 8;

  f32x4 acc[4] = {};
  for (int kb = 0; kb < KD; kb += 32) {
    __syncthreads();
    *(i32x4*)&Wt[srow * 40 + schunk] = *(const i32x4*)(Wb + (size_t)(n0 + srow) * KD + kb + schunk);
    *(i32x4*)&Xt[srow * 40 + schunk] = *(const i32x4*)(Xb + (m0 + srow) * KD + kb + schunk);
    __syncthreads();
    bfrag af = *(const bfrag*)&Wt[(wid * 16 + cc) * 40 + g * 8];
#pragma unroll
    for (int mt = 0; mt < 4; ++mt) {
      bfrag bf = *(const bfrag*)&Xt[(mt * 16 + cc) * 40 + g * 8];
      acc[mt] = __builtin_amdgcn_mfma_f32_16x16x32_bf16(af, bf, acc[mt], 0, 0, 0);
    }
  }
  const int nl = wid * 16 + g * 4;
  float bi[4];
#pragma unroll
  for (int r = 0; r < 4; ++r) bi[r] = bias[n0 + nl + r];
#pragma unroll
  for (int mt = 0; mt < 4; ++mt) {
#pragma unroll
    for (int r = 0; r < 4; ++r) {
      float v = acc[mt][r] + bi[r];
      size_t idx = ((size_t)t * NG + n0 + nl + r) * 64 + mt * 16 + cc;
      if (XP32) ((float*)XPv)[idx] = v;
      else ((unsigned short*)XPv)[idx] = f2bf(v);
    }
  }
}

// ---------------- Phase B: persistent recurrence, tagged-data mailbox (fixed poll) --------
// grid = 64: blk = bid>>4 (16 batches), slice = bid&15 (32 dims).
// Single-hop exchange: producers store (tag32|bf16x2) u64 words (relaxed agent = sc1,
// 64-bit single-copy atomic) straight from the pointwise registers — NO drains, NO
// flags, NO extra barriers. Consumers poll the data words themselves with ONE inline-asm
// batch of 16 global_load_dwordx2 sc1 + a single vmcnt(0) per round; uniform re-issue of
// all 16 on any miss (no divergence). Exact-tag accept: within a parity buffer the tag
// for step t+1 can only advance to t+3 after every WG consumed t+1 (transitive dep).
template <int XP32>
__global__ __launch_bounds__(256, 1) void lstm_rec(const unsigned short* __restrict__ Whh,
                                                   const void* __restrict__ XPv,
                                                   const float* __restrict__ bhh,
                                                   const float* __restrict__ h0,
                                                   const float* __restrict__ c0,
                                                   unsigned long long* __restrict__ mbox,
                                                   float* __restrict__ out) {
  __shared__ unsigned short hl[16 * 512];  // h block, XOR-swizzled rows (16KB)
  __shared__ float hf[16 * 33];            // h_new transpose tile (padded)

  const int tid = threadIdx.x;
  const int lane = tid & 63, wid = tid >> 6;
  const int g = lane >> 4, cc = lane & 15;
  const int blk = blockIdx.x >> 4, slice = blockIdx.x & 15;
  const int b0 = blk * 16, d0 = slice * 32;

  // ---- publish our slice of h0 (tag=1) into parity-0 mailbox, ASAP (1 word/thread)
  {
    const int lp = tid >> 4, b = tid & 15;  // local pair, batch row
    const int d = d0 + lp * 2;
    const float* hp = h0 + (size_t)(b0 + b) * KD + d;
    unsigned d32 = (unsigned)f2bf(hp[0]) | ((unsigned)f2bf(hp[1]) << 16);
    __hip_atomic_store(mbox + (size_t)blk * MB_BLK_WORDS + ((d0 >> 1) + lp) * 16 + b,
                       (1ull << 32) | (unsigned long long)d32, __ATOMIC_RELAXED,
                       __HIP_MEMORY_SCOPE_AGENT);
  }

  // ---- preload W_hh slice into registers: 2 tiles x 16 k-steps of bf16x8
  bfrag w[2][16];
#pragma unroll
  for (int j = 0; j < 2; ++j) {
    const int tt = wid * 2 + j;
    const int r = tt * 16 + cc;  // A-operand row = lane&15
    const size_t n = (size_t)(r & 3) * KD + d0 + (r >> 2);
#pragma unroll
    for (int ks = 0; ks < 16; ++ks)
      w[j][ks] = *(const bfrag*)(Whh + n * KD + ks * 32 + g * 8);
  }
  float bh[2][4], creg[2];
#pragma unroll
  for (int j = 0; j < 2; ++j) {
    const int d = d0 + (wid * 2 + j) * 4 + g;
#pragma unroll
    for (int r = 0; r < 4; ++r) bh[j][r] = bhh[r * KD + d];
    creg[j] = c0[(b0 + cc) * KD + d];
  }

  for (int t = 0; t < NT; ++t) {
    // prefetch x_proj (independent of h; drains under the first poll round)
    float xp[2][4];
#pragma unroll
    for (int j = 0; j < 2; ++j) {
      const int d = d0 + (wid * 2 + j) * 4 + g;
#pragma unroll
      for (int r = 0; r < 4; ++r) {
        size_t idx = ((size_t)t * NG + r * KD + d) * 64 + b0 + cc;
        xp[j][r] = XP32 ? ((const float*)XPv)[idx] : bf2f(((const unsigned short*)XPv)[idx]);
      }
    }
    // ---- single-hop receive: batched asm poll of 16 tagged words per thread
    const unsigned long long* mbr =
        mbox + (size_t)(t & 1) * MB_PAR_WORDS + (size_t)blk * MB_BLK_WORDS;
    const unsigned tg = (unsigned)(t + 1);
    unsigned long long q0, q1, q2, q3, q4, q5, q6, q7, q8, q9, q10, q11, q12, q13, q14, q15;
#define PISSUE(r)                                                        \
  asm volatile("global_load_dwordx2 %0, %1, %2 sc1"                      \
               : "=v"(q##r)                                              \
               : "v"((unsigned)(tid * 8 + r * 2048)), "s"(mbr));
    for (;;) {
      PISSUE(0) PISSUE(1) PISSUE(2) PISSUE(3) PISSUE(4) PISSUE(5) PISSUE(6) PISSUE(7)
      PISSUE(8) PISSUE(9) PISSUE(10) PISSUE(11) PISSUE(12) PISSUE(13) PISSUE(14) PISSUE(15)
      asm volatile("s_waitcnt vmcnt(0)" ::: "memory");
      __builtin_amdgcn_sched_barrier(0);
      unsigned ok = 1u;
#define PCHK(r) ok &= ((unsigned)(q##r >> 32) == tg) ? 1u : 0u;
      PCHK(0) PCHK(1) PCHK(2) PCHK(3) PCHK(4) PCHK(5) PCHK(6) PCHK(7)
      PCHK(8) PCHK(9) PCHK(10) PCHK(11) PCHK(12) PCHK(13) PCHK(14) PCHK(15)
      if (__all(ok)) break;
    }
#undef PISSUE
#undef PCHK
    // unpack into swizzled LDS: word (r*256+tid) = pair p = r*16 + (tid>>4), batch b = tid&15
    {
      const int b = tid & 15, pq = tid >> 4;
      const int bb = b * 1024, bx = (b & 7) << 4;
#define PUNP(r) \
  *(unsigned*)((char*)hl + bb + (((r * 16 + pq) * 4) ^ bx)) = (unsigned)q##r;
      PUNP(0) PUNP(1) PUNP(2) PUNP(3) PUNP(4) PUNP(5) PUNP(6) PUNP(7)
      PUNP(8) PUNP(9) PUNP(10) PUNP(11) PUNP(12) PUNP(13) PUNP(14) PUNP(15)
#undef PUNP
    }
    __syncthreads();
    // gates = W_slice @ h^T  (4 accumulators: chains of 8)
    f32x4 p00 = {0.f, 0.f, 0.f, 0.f}, p01 = {0.f, 0.f, 0.f, 0.f};
    f32x4 p10 = {0.f, 0.f, 0.f, 0.f}, p11 = {0.f, 0.f, 0.f, 0.f};
#pragma unroll
    for (int ks = 0; ks < 8; ++ks) {
      const int off = ks * 64 + g * 16;
      bfrag hb = *(const bfrag*)((const char*)hl + cc * 1024 + (off ^ ((cc & 7) << 4)));
      p00 = __builtin_amdgcn_mfma_f32_16x16x32_bf16(w[0][ks], hb, p00, 0, 0, 0);
      p10 = __builtin_amdgcn_mfma_f32_16x16x32_bf16(w[1][ks], hb, p10, 0, 0, 0);
    }
#pragma unroll
    for (int ks = 8; ks < 16; ++ks) {
      const int off = ks * 64 + g * 16;
      bfrag hb = *(const bfrag*)((const char*)hl + cc * 1024 + (off ^ ((cc & 7) << 4)));
      p01 = __builtin_amdgcn_mfma_f32_16x16x32_bf16(w[0][ks], hb, p01, 0, 0, 0);
      p11 = __builtin_amdgcn_mfma_f32_16x16x32_bf16(w[1][ks], hb, p11, 0, 0, 0);
    }
    const f32x4 acc0 = p00 + p01, acc1 = p10 + p11;
    // pointwise (i,f,g,o thread-local)
    float hnv[2];
#pragma unroll
    for (int j = 0; j < 2; ++j) {
      const f32x4 a = j ? acc1 : acc0;
      float gi = a[0] + xp[j][0] + bh[j][0];
      float gf = a[1] + xp[j][1] + bh[j][1];
      float gg = a[2] + xp[j][2] + bh[j][2];
      float go = a[3] + xp[j][3] + bh[j][3];
      float cn = sigm(gf) * creg[j] + sigm(gi) * tanh_f(gg);
      creg[j] = cn;
      hnv[j] = sigm(go) * tanh_f(cn);
      if (t == NT - 1) out[CT_OFF + (size_t)(b0 + cc) * KD + d0 + (wid * 8 + j * 4 + g)] = cn;
    }
    // ---- single-hop publish: pair dims via shfl, store (tag|bf16x2) words NOW; no drain
    {
      unsigned long long* mbw =
          mbox + (size_t)((t + 1) & 1) * MB_PAR_WORDS + (size_t)blk * MB_BLK_WORDS;
      const unsigned long long tagn = (unsigned long long)(unsigned)(t + 2) << 32;
      const float o0 = __shfl_xor(hnv[0], 16);
      const float o1 = __shfl_xor(hnv[1], 16);
      if (!(g & 1)) {
        const unsigned w0 = (unsigned)f2bf(hnv[0]) | ((unsigned)f2bf(o0) << 16);
        const unsigned w1 = (unsigned)f2bf(hnv[1]) | ((unsigned)f2bf(o1) << 16);
        const int p0 = (d0 >> 1) + wid * 4 + (g >> 1);
        const int p1 = p0 + 2;
        __hip_atomic_store(mbw + p0 * 16 + cc, tagn | (unsigned long long)w0,
                           __ATOMIC_RELAXED, __HIP_MEMORY_SCOPE_AGENT);
        __hip_atomic_store(mbw + p1 * 16 + cc, tagn | (unsigned long long)w1,
                           __ATOMIC_RELAXED, __HIP_MEMORY_SCOPE_AGENT);
      }
    }
    // transpose h_new for coalesced fp32 output stores (off critical path)
#pragma unroll
    for (int j = 0; j < 2; ++j) hf[cc * 33 + (wid * 8 + j * 4 + g)] = hnv[j];
    __syncthreads();
    if (tid < 128) {
      const int b = tid >> 3, dg = (tid & 7) * 4;
      float4 hv;
      hv.x = hf[b * 33 + dg];
      hv.y = hf[b * 33 + dg + 1];
      hv.z = hf[b * 33 + dg + 2];
      hv.w = hf[b * 33 + dg + 3];
      *(float4*)(out + (size_t)t * NB * KD + (size_t)(b0 + b) * KD + d0 + dg) = hv;
      if (t == NT - 1)
        *(float4*)(out + HT_OFF + (size_t)(b0 + b) * KD + d0 + dg) = hv;
    }
  }
}

extern "C" void kernel_launch(void* const* d_in, const int* in_sizes, int n_in,
                              void* d_out, int out_size, void* d_ws, size_t ws_size,
                              hipStream_t stream) {
  const float* x = (const float*)d_in[0];
  const float* h0 = (const float*)d_in[1];
  const float* c0 = (const float*)d_in[2];
  const float* Wih = (const float*)d_in[3];
  const float* Whh = (const float*)d_in[4];
  const float* bih = (const float*)d_in[5];
  const float* bhh = (const float*)d_in[6];
  float* out = (float*)d_out;
  char* ws = (char*)d_ws;

  unsigned long long* mbox = (unsigned long long*)ws;                      // 256KB
  unsigned short* WhhB = (unsigned short*)(ws + MB_BYTES);                 // 2MB
  unsigned short* WihB = (unsigned short*)(ws + MB_BYTES + 2097152);       // 2MB
  unsigned short* XB = (unsigned short*)(ws + MB_BYTES + 2 * 2097152);     // 32MB
  const size_t xp_off = MB_BYTES + 2ull * 2097152 + 33554432;
  void* XP = (void*)(ws + xp_off);
  const bool xp32 = ws_size >= xp_off + (size_t)NT * NG * 64 * 4;

  hipMemsetAsync(ws, 0, MB_BYTES, stream);  // reset mailbox tags (poison/replay safe)

  const int nx8 = NT * NB * KD / 8;
  const int nw8 = NG * KD / 8;
  cvt_bf16<<<dim3(nx8 / 256), 256, 0, stream>>>(x, XB, nx8);
  cvt_bf16<<<dim3(nw8 / 256), 256, 0, stream>>>(Wih, WihB, nw8);
  cvt_bf16<<<dim3(nw8 / 256), 256, 0, stream>>>(Whh, WhhB, nw8);

  if (xp32) {
    xproj_gemm<1><<<dim3(NG / 64, NT), 256, 0, stream>>>(WihB, XB, bih, XP);
    lstm_rec<1><<<dim3(GB * GH), 256, 0, stream>>>(WhhB, XP, bhh, h0, c0, mbox, out);
  } else {
    xproj_gemm<0><<<dim3(NG / 64, NT), 256, 0, stream>>>(WihB, XB, bih, XP);
    lstm_rec<0><<<dim3(GB * GH), 256, 0, stream>>>(WhhB, XP, bhh, h0, c0, mbox, out);
  }
}